// Round 2
// baseline (881.050 us; speedup 1.0000x reference)
//
#include <hip/hip_runtime.h>
#include <hip/hip_bf16.h>

typedef __bf16 bf16x8 __attribute__((ext_vector_type(8)));
typedef float  f32x4  __attribute__((ext_vector_type(4)));

#define MFMA16(a, b, c) __builtin_amdgcn_mfma_f32_16x16x32_bf16((a), (b), (c), 0, 0, 0)

#define GLOBAL_AS(p) ((const __attribute__((address_space(1))) void*)(p))
#define LDS_AS(p)    ((__attribute__((address_space(3))) void*)(p))

// ---------------------------------------------------------------------------
// fp32 -> bf16 elementwise convert.  Each thread converts 8 elements.
// ---------------------------------------------------------------------------
__global__ __launch_bounds__(256) void cvt_bf16_kernel(const float* __restrict__ in,
                                                       __bf16* __restrict__ out)
{
    const int idx = blockIdx.x * 256 + threadIdx.x;
    const float4* p = (const float4*)in + (size_t)idx * 2;
    float4 a = p[0], b = p[1];
    bf16x8 o;
    o[0] = (__bf16)a.x; o[1] = (__bf16)a.y; o[2] = (__bf16)a.z; o[3] = (__bf16)a.w;
    o[4] = (__bf16)b.x; o[5] = (__bf16)b.y; o[6] = (__bf16)b.z; o[7] = (__bf16)b.w;
    ((bf16x8*)out)[idx] = o;
}

// ---------------------------------------------------------------------------
// Transpose + convert: Bt[n][k] = (bf16)W[k][n].  W is K x N fp32.
// block (32,8), grid (N/32, K/32).
// ---------------------------------------------------------------------------
__global__ __launch_bounds__(256) void transpose_cvt_kernel(const float* __restrict__ W,
                                                            __bf16* __restrict__ Bt,
                                                            int K, int N)
{
    __shared__ float t[32][33];
    const int n0 = blockIdx.x * 32, k0 = blockIdx.y * 32;
    const int x = threadIdx.x, y = threadIdx.y;
#pragma unroll
    for (int r = 0; r < 4; ++r)
        t[y + r * 8][x] = W[(size_t)(k0 + y + r * 8) * N + n0 + x];
    __syncthreads();
#pragma unroll
    for (int r = 0; r < 4; ++r)
        Bt[(size_t)(n0 + y + r * 8) * K + k0 + x] = (__bf16)t[x][y + r * 8];
}

// ---------------------------------------------------------------------------
// GEMM (m97 structure): C[M][N] = A[M][K] * Bt[N][K]^T, bf16 inputs.
// Block 256 thr (4 waves 2x2), tile 128x128, BK=32.
// Staging via global_load_lds width=16 (contiguous LDS, no padding).
// ---------------------------------------------------------------------------
template <typename TC>
__global__ __launch_bounds__(256) void gemm_bt(const __bf16* __restrict__ A,
                                               const __bf16* __restrict__ Bt,
                                               TC* __restrict__ C,
                                               int M, int N, int K)
{
    __shared__ __bf16 As[128 * 32];
    __shared__ __bf16 Bs[128 * 32];

    const int tid  = threadIdx.x;
    const int wave = tid >> 6, lane = tid & 63;
    const int quad = lane >> 4, l16 = lane & 15;
    const int wm = (wave >> 1) * 64, wn = (wave & 1) * 64;
    const int bm = blockIdx.y * 128, bn = blockIdx.x * 128;

    f32x4 acc[4][4] = {};

    for (int k0 = 0; k0 < K; k0 += 32) {
        __syncthreads();
#pragma unroll
        for (int c = 0; c < 2; ++c) {
            const int off = tid * 16 + c * 4096;   // byte offset into 8 KB tile
            const int row = off >> 6;              // 64 B (32 bf16) per row
            const int kb  = (off & 63) >> 1;       // bf16 offset within row
            const __bf16* ga = A  + (size_t)(bm + row) * K + k0 + kb;
            const __bf16* gb = Bt + (size_t)(bn + row) * K + k0 + kb;
            __builtin_amdgcn_global_load_lds(GLOBAL_AS(ga), LDS_AS(As + (off >> 1)), 16, 0, 0);
            __builtin_amdgcn_global_load_lds(GLOBAL_AS(gb), LDS_AS(Bs + (off >> 1)), 16, 0, 0);
        }
        __syncthreads();   // compiler emits vmcnt(0) drain here

        bf16x8 af[4];
#pragma unroll
        for (int mi = 0; mi < 4; ++mi)
            af[mi] = *(const bf16x8*)&As[(wm + mi * 16 + l16) * 32 + quad * 8];
#pragma unroll
        for (int ni = 0; ni < 4; ++ni) {
            bf16x8 bfr = *(const bf16x8*)&Bs[(wn + ni * 16 + l16) * 32 + quad * 8];
#pragma unroll
            for (int mi = 0; mi < 4; ++mi)
                acc[mi][ni] = MFMA16(af[mi], bfr, acc[mi][ni]);
        }
    }
    // C/D layout: col = lane&15, row = quad*4 + reg
#pragma unroll
    for (int mi = 0; mi < 4; ++mi)
#pragma unroll
        for (int ni = 0; ni < 4; ++ni)
#pragma unroll
            for (int r = 0; r < 4; ++r) {
                int row = bm + wm + mi * 16 + quad * 4 + r;
                int col = bn + wn + ni * 16 + l16;
                C[(size_t)row * N + col] = (TC)acc[mi][ni][r];
            }
}

// ---------------------------------------------------------------------------
// RoPE + split of fused kv + Vt build.  q in-place (pre-scaled by log2(e)/16);
// kv[bs][512]: cols 0..255 = k, 256..511 = v.  Outputs roped k and vT.
// ---------------------------------------------------------------------------
__global__ __launch_bounds__(256) void rope_kernel(__bf16* __restrict__ q,
                                                   const __bf16* __restrict__ kv,
                                                   __bf16* __restrict__ kout,
                                                   __bf16* __restrict__ vT)
{
    const int bs = blockIdx.x;              // b*2048 + s
    const int b = bs >> 11, s = bs & 2047;
    const int t = threadIdx.x;
    const int i = t & 127;                  // rotary pair index (d and d+128)

    const float theta = (float)s * exp2f((float)i * (-13.287712379549449f / 128.f));
    float sn, cs;
    sincosf(theta, &sn, &cs);
    const float QS = 0.09016843787599907f;  // log2(e) / sqrt(D)

#pragma unroll
    for (int jj = 0; jj < 4; ++jj) {
        int p  = t + 256 * jj;              // 1024 (h, i) pairs
        int hh = p >> 7;
        size_t base = (size_t)bs * 2048 + (size_t)hh * 256 + i;
        float x1 = (float)q[base];
        float x2 = (float)q[base + 128];
        q[base]       = (__bf16)((x1 * cs - x2 * sn) * QS);
        q[base + 128] = (__bf16)((x2 * cs + x1 * sn) * QS);
    }
    if (t < 128) {
        float x1 = (float)kv[(size_t)bs * 512 + i];
        float x2 = (float)kv[(size_t)bs * 512 + i + 128];
        kout[(size_t)bs * 256 + i]       = (__bf16)(x1 * cs - x2 * sn);
        kout[(size_t)bs * 256 + i + 128] = (__bf16)(x2 * cs + x1 * sn);
    }
    // v transpose: vT[b][d][s] = v[b][s][d]
    vT[((size_t)b * 256 + t) * 2048 + s] = kv[(size_t)bs * 512 + 256 + t];
}

// ---------------------------------------------------------------------------
// Flash attention (causal), no K/V LDS staging: fragments read directly from
// global (K/Vt are small and L1/L2-resident).  grid = (32 qt, H, B), 256 thr.
// K-tile = 64 keys.  No __syncthreads in the loop; P transposes through
// per-wave LDS.  qt reversed so longest blocks launch first.
// ---------------------------------------------------------------------------
__global__ __launch_bounds__(256) void attn_kernel(const __bf16* __restrict__ qg,
                                                   const __bf16* __restrict__ kg,
                                                   const __bf16* __restrict__ vTg,
                                                   __bf16* __restrict__ og)
{
    __shared__ __bf16 Ps[4][16][72];   // per-wave P tile [qrow][key], pad 64->72

    const int b = blockIdx.z, h = blockIdx.y;
    const int qt = (int)gridDim.x - 1 - (int)blockIdx.x;
    const int q0 = qt * 64;
    const int tid  = threadIdx.x;
    const int wave = tid >> 6, lane = tid & 63;
    const int quad = lane >> 4, l16 = lane & 15;

    // Q fragments (A-layout: m = lane&15, k = quad*8 + j)
    const int qrow = q0 + wave * 16 + l16;
    const __bf16* qptr = qg + (size_t)(b * 2048 + qrow) * 2048 + h * 256;
    bf16x8 qf[8];
#pragma unroll
    for (int dc = 0; dc < 8; ++dc)
        qf[dc] = *(const bf16x8*)(qptr + dc * 32 + quad * 8);

    f32x4 oacc[16] = {};
    float m_r[4] = {-1e30f, -1e30f, -1e30f, -1e30f};
    float l_r[4] = {0.f, 0.f, 0.f, 0.f};

    const __bf16* kbase = kg  + (size_t)b * 2048 * 256;
    const __bf16* vbase = vTg + (size_t)b * 256 * 2048;

    for (int j0 = 0; j0 <= q0; j0 += 64) {
        // ---- S = Q K^T over 64 keys (4 n-tiles) ----
        f32x4 sc[4] = {};
#pragma unroll
        for (int nt = 0; nt < 4; ++nt) {
            const __bf16* kp = kbase + (size_t)(j0 + nt * 16 + l16) * 256 + quad * 8;
#pragma unroll
            for (int dc = 0; dc < 8; ++dc) {
                bf16x8 kf = *(const bf16x8*)(kp + dc * 32);
                sc[nt] = MFMA16(qf[dc], kf, sc[nt]);
            }
        }
        if (j0 == q0) {   // diagonal tile: causal mask
#pragma unroll
            for (int nt = 0; nt < 4; ++nt) {
                int key = j0 + nt * 16 + l16;
#pragma unroll
                for (int r = 0; r < 4; ++r) {
                    int row = q0 + wave * 16 + quad * 4 + r;
                    if (key > row) sc[nt][r] = -1e30f;
                }
            }
        }
        // ---- online softmax (exp2 domain; scale folded into Q) ----
#pragma unroll
        for (int r = 0; r < 4; ++r) {
            float mx = fmaxf(fmaxf(sc[0][r], sc[1][r]), fmaxf(sc[2][r], sc[3][r]));
#pragma unroll
            for (int off = 1; off < 16; off <<= 1)
                mx = fmaxf(mx, __shfl_xor(mx, off, 64));
            float mnew  = fmaxf(m_r[r], mx);
            float alpha = exp2f(m_r[r] - mnew);
            m_r[r] = mnew;
            float rs = 0.f;
#pragma unroll
            for (int nt = 0; nt < 4; ++nt) {
                float p = exp2f(sc[nt][r] - mnew);
                sc[nt][r] = p;
                rs += p;
            }
#pragma unroll
            for (int off = 1; off < 16; off <<= 1)
                rs += __shfl_xor(rs, off, 64);
            l_r[r] = l_r[r] * alpha + rs;
#pragma unroll
            for (int t = 0; t < 16; ++t)
                oacc[t][r] *= alpha;
        }
        // ---- P: C-layout -> per-wave LDS -> A-layout (in-order, no barrier) --
#pragma unroll
        for (int nt = 0; nt < 4; ++nt)
#pragma unroll
            for (int r = 0; r < 4; ++r)
                Ps[wave][quad * 4 + r][nt * 16 + l16] = (__bf16)sc[nt][r];
        bf16x8 pf0 = *(const bf16x8*)&Ps[wave][l16][quad * 8];
        bf16x8 pf1 = *(const bf16x8*)&Ps[wave][l16][32 + quad * 8];
        // ---- O += P V (16 d-tiles x 2 k-chunks), V frags direct from global --
#pragma unroll
        for (int vt = 0; vt < 16; ++vt) {
            const __bf16* vp = vbase + (size_t)(vt * 16 + l16) * 2048 + j0 + quad * 8;
            bf16x8 vf0 = *(const bf16x8*)(vp);
            bf16x8 vf1 = *(const bf16x8*)(vp + 32);
            oacc[vt] = MFMA16(pf0, vf0, oacc[vt]);
            oacc[vt] = MFMA16(pf1, vf1, oacc[vt]);
        }
    }
    // ---- normalize + store ----
    float invl[4];
#pragma unroll
    for (int r = 0; r < 4; ++r) invl[r] = 1.f / l_r[r];
#pragma unroll
    for (int vt = 0; vt < 16; ++vt)
#pragma unroll
        for (int r = 0; r < 4; ++r) {
            int row = q0 + wave * 16 + quad * 4 + r;
            int col = h * 256 + vt * 16 + l16;
            og[(size_t)(b * 2048 + row) * 2048 + col] = (__bf16)(oacc[vt][r] * invl[r]);
        }
}

// ---------------------------------------------------------------------------
// Workspace layout (byte offsets, MiB):
//   hb   [4096][2048] bf16 @  0   (16)   hidden in bf16
//   q    [4096][2048] bf16 @ 16   (16)
//   kv   [4096][512]  bf16 @ 32   ( 4)   fused K|V projection
//   kb   [4096][256]  bf16 @ 36   ( 2)   roped K
//   vT   [2][256][2048]   @ 38   ( 2)
//   ob   [4096][2048] bf16 @ 40   (16)   attention output
//   Wqt  [2048][2048] bf16 @ 56   ( 8)
//   Wkvt [512][2048]  bf16 @ 64   ( 2)
//   Wot  [2048][2048] bf16 @ 66   ( 8)   total 74 MiB
// ---------------------------------------------------------------------------
extern "C" void kernel_launch(void* const* d_in, const int* in_sizes, int n_in,
                              void* d_out, int out_size, void* d_ws, size_t ws_size,
                              hipStream_t stream)
{
    (void)in_sizes; (void)n_in; (void)out_size; (void)ws_size;
    const float* hidden = (const float*)d_in[0];
    const float* Wq = (const float*)d_in[3];
    const float* Wk = (const float*)d_in[4];
    const float* Wv = (const float*)d_in[5];
    const float* Wo = (const float*)d_in[6];

    char* ws = (char*)d_ws;
    __bf16* hb   = (__bf16*)(ws);
    __bf16* qb   = (__bf16*)(ws + (16u << 20));
    __bf16* kvb  = (__bf16*)(ws + (32u << 20));
    __bf16* kb   = (__bf16*)(ws + (36u << 20));
    __bf16* vTb  = (__bf16*)(ws + (38u << 20));
    __bf16* ob   = (__bf16*)(ws + (40u << 20));
    __bf16* Wqt  = (__bf16*)(ws + (56u << 20));
    __bf16* Wkvt = (__bf16*)(ws + (64u << 20));
    __bf16* Wot  = (__bf16*)(ws + (66u << 20));
    float* out = (float*)d_out;

    dim3 blk(256);
    dim3 tblk(32, 8);
    // prep: convert + transpose
    cvt_bf16_kernel<<<dim3(4096), blk, 0, stream>>>(hidden, hb);
    transpose_cvt_kernel<<<dim3(64, 64), tblk, 0, stream>>>(Wq, Wqt, 2048, 2048);
    transpose_cvt_kernel<<<dim3(8, 64), tblk, 0, stream>>>(Wk, Wkvt, 2048, 256);
    transpose_cvt_kernel<<<dim3(8, 64), tblk, 0, stream>>>(Wv, Wkvt + (size_t)256 * 2048, 2048, 256);
    transpose_cvt_kernel<<<dim3(64, 64), tblk, 0, stream>>>(Wo, Wot, 2048, 2048);
    // projections
    gemm_bt<__bf16><<<dim3(16, 32), blk, 0, stream>>>(hb, Wqt, qb, 4096, 2048, 2048);
    gemm_bt<__bf16><<<dim3(4, 32), blk, 0, stream>>>(hb, Wkvt, kvb, 4096, 512, 2048);
    // rope + layout
    rope_kernel<<<dim3(4096), blk, 0, stream>>>(qb, kvb, kb, vTb);
    // attention
    attn_kernel<<<dim3(32, 8, 2), blk, 0, stream>>>(qb, kb, vTb, ob);
    // output projection
    gemm_bt<float><<<dim3(16, 32), blk, 0, stream>>>(ob, Wot, out, 4096, 2048, 2048);
}

// Round 3
// 439.316 us; speedup vs baseline: 2.0055x; 2.0055x over previous
//
#include <hip/hip_runtime.h>
#include <hip/hip_bf16.h>

typedef __bf16 bf16x8 __attribute__((ext_vector_type(8)));
typedef float  f32x4  __attribute__((ext_vector_type(4)));

#define MFMA16(a, b, c) __builtin_amdgcn_mfma_f32_16x16x32_bf16((a), (b), (c), 0, 0, 0)

#define GLOBAL_AS(p) ((const __attribute__((address_space(1))) void*)(p))
#define LDS_AS(p)    ((__attribute__((address_space(3))) void*)(p))

// ---------------------------------------------------------------------------
// fp32 -> bf16 elementwise convert.  Each thread converts 8 elements.
// ---------------------------------------------------------------------------
__global__ __launch_bounds__(256) void cvt_bf16_kernel(const float* __restrict__ in,
                                                       __bf16* __restrict__ out)
{
    const int idx = blockIdx.x * 256 + threadIdx.x;
    const float4* p = (const float4*)in + (size_t)idx * 2;
    float4 a = p[0], b = p[1];
    bf16x8 o;
    o[0] = (__bf16)a.x; o[1] = (__bf16)a.y; o[2] = (__bf16)a.z; o[3] = (__bf16)a.w;
    o[4] = (__bf16)b.x; o[5] = (__bf16)b.y; o[6] = (__bf16)b.z; o[7] = (__bf16)b.w;
    ((bf16x8*)out)[idx] = o;
}

// ---------------------------------------------------------------------------
// Transpose + convert: Bt[n][k] = (bf16)W[k][n].  W is K x N fp32.
// block (32,8), grid (N/32, K/32).
// ---------------------------------------------------------------------------
__global__ __launch_bounds__(256) void transpose_cvt_kernel(const float* __restrict__ W,
                                                            __bf16* __restrict__ Bt,
                                                            int K, int N)
{
    __shared__ float t[32][33];
    const int n0 = blockIdx.x * 32, k0 = blockIdx.y * 32;
    const int x = threadIdx.x, y = threadIdx.y;
#pragma unroll
    for (int r = 0; r < 4; ++r)
        t[y + r * 8][x] = W[(size_t)(k0 + y + r * 8) * N + n0 + x];
    __syncthreads();
#pragma unroll
    for (int r = 0; r < 4; ++r)
        Bt[(size_t)(n0 + y + r * 8) * K + k0 + x] = (__bf16)t[x][y + r * 8];
}

// ---------------------------------------------------------------------------
// GEMM (m97 structure): C[M][N] = A[M][K] * Bt[N][K]^T, bf16 inputs.
// Block 256 thr (4 waves 2x2), tile 128x128, BK=32.
// Staging via global_load_lds width=16 (contiguous LDS, no padding).
// ---------------------------------------------------------------------------
template <typename TC>
__global__ __launch_bounds__(256) void gemm_bt(const __bf16* __restrict__ A,
                                               const __bf16* __restrict__ Bt,
                                               TC* __restrict__ C,
                                               int M, int N, int K)
{
    __shared__ __bf16 As[128 * 32];
    __shared__ __bf16 Bs[128 * 32];

    const int tid  = threadIdx.x;
    const int wave = tid >> 6, lane = tid & 63;
    const int quad = lane >> 4, l16 = lane & 15;
    const int wm = (wave >> 1) * 64, wn = (wave & 1) * 64;
    const int bm = blockIdx.y * 128, bn = blockIdx.x * 128;

    f32x4 acc[4][4] = {};

    for (int k0 = 0; k0 < K; k0 += 32) {
        __syncthreads();
#pragma unroll
        for (int c = 0; c < 2; ++c) {
            const int off = tid * 16 + c * 4096;   // byte offset into 8 KB tile
            const int row = off >> 6;              // 64 B (32 bf16) per row
            const int kb  = (off & 63) >> 1;       // bf16 offset within row
            const __bf16* ga = A  + (size_t)(bm + row) * K + k0 + kb;
            const __bf16* gb = Bt + (size_t)(bn + row) * K + k0 + kb;
            __builtin_amdgcn_global_load_lds(GLOBAL_AS(ga), LDS_AS(As + (off >> 1)), 16, 0, 0);
            __builtin_amdgcn_global_load_lds(GLOBAL_AS(gb), LDS_AS(Bs + (off >> 1)), 16, 0, 0);
        }
        __syncthreads();   // compiler emits vmcnt(0) drain here

        bf16x8 af[4];
#pragma unroll
        for (int mi = 0; mi < 4; ++mi)
            af[mi] = *(const bf16x8*)&As[(wm + mi * 16 + l16) * 32 + quad * 8];
#pragma unroll
        for (int ni = 0; ni < 4; ++ni) {
            bf16x8 bfr = *(const bf16x8*)&Bs[(wn + ni * 16 + l16) * 32 + quad * 8];
#pragma unroll
            for (int mi = 0; mi < 4; ++mi)
                acc[mi][ni] = MFMA16(af[mi], bfr, acc[mi][ni]);
        }
    }
    // C/D layout: col = lane&15, row = quad*4 + reg
#pragma unroll
    for (int mi = 0; mi < 4; ++mi)
#pragma unroll
        for (int ni = 0; ni < 4; ++ni)
#pragma unroll
            for (int r = 0; r < 4; ++r) {
                int row = bm + wm + mi * 16 + quad * 4 + r;
                int col = bn + wn + ni * 16 + l16;
                C[(size_t)row * N + col] = (TC)acc[mi][ni][r];
            }
}

// ---------------------------------------------------------------------------
// RoPE + split of fused kv + Vt build.  q in-place (pre-scaled by log2(e)/16);
// kv[bs][512]: cols 0..255 = k, 256..511 = v.  Outputs roped k and vT.
// ---------------------------------------------------------------------------
__global__ __launch_bounds__(256) void rope_kernel(__bf16* __restrict__ q,
                                                   const __bf16* __restrict__ kv,
                                                   __bf16* __restrict__ kout,
                                                   __bf16* __restrict__ vT)
{
    const int bs = blockIdx.x;              // b*2048 + s
    const int b = bs >> 11, s = bs & 2047;
    const int t = threadIdx.x;
    const int i = t & 127;                  // rotary pair index (d and d+128)

    const float theta = (float)s * exp2f((float)i * (-13.287712379549449f / 128.f));
    float sn, cs;
    sincosf(theta, &sn, &cs);
    const float QS = 0.09016843787599907f;  // log2(e) / sqrt(D)

#pragma unroll
    for (int jj = 0; jj < 4; ++jj) {
        int p  = t + 256 * jj;              // 1024 (h, i) pairs
        int hh = p >> 7;
        size_t base = (size_t)bs * 2048 + (size_t)hh * 256 + i;
        float x1 = (float)q[base];
        float x2 = (float)q[base + 128];
        q[base]       = (__bf16)((x1 * cs - x2 * sn) * QS);
        q[base + 128] = (__bf16)((x2 * cs + x1 * sn) * QS);
    }
    if (t < 128) {
        float x1 = (float)kv[(size_t)bs * 512 + i];
        float x2 = (float)kv[(size_t)bs * 512 + i + 128];
        kout[(size_t)bs * 256 + i]       = (__bf16)(x1 * cs - x2 * sn);
        kout[(size_t)bs * 256 + i + 128] = (__bf16)(x2 * cs + x1 * sn);
    }
    // v transpose: vT[b][d][s] = v[b][s][d]
    vT[((size_t)b * 256 + t) * 2048 + s] = kv[(size_t)bs * 512 + 256 + t];
}

// ---------------------------------------------------------------------------
// Flash attention (causal), LDS-staged K/Vt with XOR-swizzled layout and
// global_load_lds(width=16) staging.  grid = (32 qt, H, B), 256 thr (4 waves).
// K-tile = 64 keys.  LDS: K 32 KB + Vt 32 KB + P 4.5 KB = 69 KB (2 blk/CU).
//
// Swizzle: a tile row of R 16B-chunks stores chunk c at slot (c ^ (row & 7)).
// Permutation is applied on the GLOBAL address during staging (LDS side of
// global_load_lds must stay wave-uniform-base + lane*16).  Fragment reads
// then hit an even 2-way bank spread instead of 16-way same-bank.
// ---------------------------------------------------------------------------
__global__ __launch_bounds__(256) void attn_kernel(const __bf16* __restrict__ qg,
                                                   const __bf16* __restrict__ kg,
                                                   const __bf16* __restrict__ vTg,
                                                   __bf16* __restrict__ og)
{
    __shared__ __bf16 Ks[64 * 256];    // 64 keys x 256 d (swizzled), 32 KB
    __shared__ __bf16 Vs[256 * 64];    // 256 d x 64 keys (swizzled), 32 KB
    __shared__ __bf16 Ps[4][16][72];   // per-wave P [qrow][key], pad 64->72

    const int b = blockIdx.z, h = blockIdx.y;
    const int qt = (int)gridDim.x - 1 - (int)blockIdx.x;
    const int q0 = qt * 64;
    const int tid  = threadIdx.x;
    const int wave = tid >> 6, lane = tid & 63;
    const int quad = lane >> 4, l16 = lane & 15;
    const int xork = l16 & 7;          // swizzle key for fragment reads

    // Q fragments (A-layout: m = lane&15, k = quad*8 + j)
    const int qrow = q0 + wave * 16 + l16;
    const __bf16* qptr = qg + (size_t)(b * 2048 + qrow) * 2048 + h * 256;
    bf16x8 qf[8];
#pragma unroll
    for (int dc = 0; dc < 8; ++dc)
        qf[dc] = *(const bf16x8*)(qptr + dc * 32 + quad * 8);

    f32x4 oacc[16] = {};
    float m_r[4] = {-1e30f, -1e30f, -1e30f, -1e30f};
    float l_r[4] = {0.f, 0.f, 0.f, 0.f};

    // ---- staging address precompute (j0-independent) ----
    // K tile: 64 rows x 32 chunks.  Round p (8 rounds): thread t handles LDS
    // chunk L = t + 256p -> key = (t>>5) + 8p, global chunk c = (t&31)^(key&7).
    const int kKey0 = tid >> 5;                       // 0..7
    const int kC    = (tid & 31) ^ (kKey0 & 7);       // constant across p
    const __bf16* kstage0 = kg + (size_t)b * 2048 * 256 + (size_t)kKey0 * 256 + kC * 8;
    // V tile: 256 rows x 8 chunks.  Round p: L = t + 256p -> d = (t>>3) + 32p,
    // global chunk c = (t&7)^(d&7) (constant across p).
    const int vD0 = tid >> 3;                         // 0..31
    const int vC  = (tid & 7) ^ (vD0 & 7);
    const __bf16* vstage0 = vTg + (size_t)b * 256 * 2048 + (size_t)vD0 * 2048 + vC * 8;

    // precomputed fragment-read slot indices
    int ckK[8];
#pragma unroll
    for (int dc = 0; dc < 8; ++dc) ckK[dc] = (dc * 4 + quad) ^ xork;
    const int chV0 = quad ^ xork;          // V slot for keys 0..31 (c = quad)
    const int chV1 = (4 + quad) ^ xork;    // V slot for keys 32..63

    for (int j0 = 0; j0 <= q0; j0 += 64) {
        __syncthreads();
        // ---- stage K (8 rounds) + Vt (8 rounds), async 16B direct-to-LDS ----
        const __bf16* kst = kstage0 + (size_t)j0 * 256;
        const __bf16* vst = vstage0 + j0;
#pragma unroll
        for (int p = 0; p < 8; ++p)
            __builtin_amdgcn_global_load_lds(GLOBAL_AS(kst + (size_t)p * 2048),
                                             LDS_AS(Ks + tid * 8 + p * 2048), 16, 0, 0);
#pragma unroll
        for (int p = 0; p < 8; ++p)
            __builtin_amdgcn_global_load_lds(GLOBAL_AS(vst + (size_t)p * 32 * 2048),
                                             LDS_AS(Vs + tid * 8 + p * 2048), 16, 0, 0);
        __syncthreads();   // vmcnt(0) drain -> tile visible

        // ---- S = Q K^T over 64 keys (4 n-tiles) ----
        f32x4 sc[4] = {};
#pragma unroll
        for (int nt = 0; nt < 4; ++nt) {
            const __bf16* krow = &Ks[(nt * 16 + l16) * 256];
#pragma unroll
            for (int dc = 0; dc < 8; ++dc) {
                bf16x8 kf = *(const bf16x8*)(krow + ckK[dc] * 8);
                sc[nt] = MFMA16(qf[dc], kf, sc[nt]);
            }
        }
        if (j0 == q0) {   // diagonal tile: causal mask
#pragma unroll
            for (int nt = 0; nt < 4; ++nt) {
                int key = j0 + nt * 16 + l16;
#pragma unroll
                for (int r = 0; r < 4; ++r) {
                    int row = q0 + wave * 16 + quad * 4 + r;
                    if (key > row) sc[nt][r] = -1e30f;
                }
            }
        }
        // ---- online softmax (exp2 domain; scale folded into Q) ----
#pragma unroll
        for (int r = 0; r < 4; ++r) {
            float mx = fmaxf(fmaxf(sc[0][r], sc[1][r]), fmaxf(sc[2][r], sc[3][r]));
#pragma unroll
            for (int off = 1; off < 16; off <<= 1)
                mx = fmaxf(mx, __shfl_xor(mx, off, 64));
            float mnew  = fmaxf(m_r[r], mx);
            float alpha = exp2f(m_r[r] - mnew);
            m_r[r] = mnew;
            float rs = 0.f;
#pragma unroll
            for (int nt = 0; nt < 4; ++nt) {
                float p = exp2f(sc[nt][r] - mnew);
                sc[nt][r] = p;
                rs += p;
            }
#pragma unroll
            for (int off = 1; off < 16; off <<= 1)
                rs += __shfl_xor(rs, off, 64);
            l_r[r] = l_r[r] * alpha + rs;
#pragma unroll
            for (int t = 0; t < 16; ++t)
                oacc[t][r] *= alpha;
        }
        // ---- P: C-layout -> per-wave LDS -> A-layout (in-order, no barrier) --
#pragma unroll
        for (int nt = 0; nt < 4; ++nt)
#pragma unroll
            for (int r = 0; r < 4; ++r)
                Ps[wave][quad * 4 + r][nt * 16 + l16] = (__bf16)sc[nt][r];
        bf16x8 pf0 = *(const bf16x8*)&Ps[wave][l16][quad * 8];
        bf16x8 pf1 = *(const bf16x8*)&Ps[wave][l16][32 + quad * 8];
        // ---- O += P V (16 d-tiles x 2 key-halves) ----
#pragma unroll
        for (int dt = 0; dt < 16; ++dt) {
            const __bf16* vrow = &Vs[(dt * 16 + l16) * 64];
            bf16x8 vf0 = *(const bf16x8*)(vrow + chV0 * 8);
            bf16x8 vf1 = *(const bf16x8*)(vrow + chV1 * 8);
            oacc[dt] = MFMA16(pf0, vf0, oacc[dt]);
            oacc[dt] = MFMA16(pf1, vf1, oacc[dt]);
        }
    }
    // ---- normalize + store ----
    float invl[4];
#pragma unroll
    for (int r = 0; r < 4; ++r) invl[r] = 1.f / l_r[r];
#pragma unroll
    for (int dt = 0; dt < 16; ++dt)
#pragma unroll
        for (int r = 0; r < 4; ++r) {
            int row = q0 + wave * 16 + quad * 4 + r;
            int col = h * 256 + dt * 16 + l16;
            og[(size_t)(b * 2048 + row) * 2048 + col] = (__bf16)(oacc[dt][r] * invl[r]);
        }
}

// ---------------------------------------------------------------------------
// Workspace layout (byte offsets, MiB):
//   hb   [4096][2048] bf16 @  0   (16)   hidden in bf16
//   q    [4096][2048] bf16 @ 16   (16)
//   kv   [4096][512]  bf16 @ 32   ( 4)   fused K|V projection
//   kb   [4096][256]  bf16 @ 36   ( 2)   roped K
//   vT   [2][256][2048]   @ 38   ( 2)
//   ob   [4096][2048] bf16 @ 40   (16)   attention output
//   Wqt  [2048][2048] bf16 @ 56   ( 8)
//   Wkvt [512][2048]  bf16 @ 64   ( 2)
//   Wot  [2048][2048] bf16 @ 66   ( 8)   total 74 MiB
// ---------------------------------------------------------------------------
extern "C" void kernel_launch(void* const* d_in, const int* in_sizes, int n_in,
                              void* d_out, int out_size, void* d_ws, size_t ws_size,
                              hipStream_t stream)
{
    (void)in_sizes; (void)n_in; (void)out_size; (void)ws_size;
    const float* hidden = (const float*)d_in[0];
    const float* Wq = (const float*)d_in[3];
    const float* Wk = (const float*)d_in[4];
    const float* Wv = (const float*)d_in[5];
    const float* Wo = (const float*)d_in[6];

    char* ws = (char*)d_ws;
    __bf16* hb   = (__bf16*)(ws);
    __bf16* qb   = (__bf16*)(ws + (16u << 20));
    __bf16* kvb  = (__bf16*)(ws + (32u << 20));
    __bf16* kb   = (__bf16*)(ws + (36u << 20));
    __bf16* vTb  = (__bf16*)(ws + (38u << 20));
    __bf16* ob   = (__bf16*)(ws + (40u << 20));
    __bf16* Wqt  = (__bf16*)(ws + (56u << 20));
    __bf16* Wkvt = (__bf16*)(ws + (64u << 20));
    __bf16* Wot  = (__bf16*)(ws + (66u << 20));
    float* out = (float*)d_out;

    dim3 blk(256);
    dim3 tblk(32, 8);
    // prep: convert + transpose
    cvt_bf16_kernel<<<dim3(4096), blk, 0, stream>>>(hidden, hb);
    transpose_cvt_kernel<<<dim3(64, 64), tblk, 0, stream>>>(Wq, Wqt, 2048, 2048);
    transpose_cvt_kernel<<<dim3(8, 64), tblk, 0, stream>>>(Wk, Wkvt, 2048, 256);
    transpose_cvt_kernel<<<dim3(8, 64), tblk, 0, stream>>>(Wv, Wkvt + (size_t)256 * 2048, 2048, 256);
    transpose_cvt_kernel<<<dim3(64, 64), tblk, 0, stream>>>(Wo, Wot, 2048, 2048);
    // projections
    gemm_bt<__bf16><<<dim3(16, 32), blk, 0, stream>>>(hb, Wqt, qb, 4096, 2048, 2048);
    gemm_bt<__bf16><<<dim3(4, 32), blk, 0, stream>>>(hb, Wkvt, kvb, 4096, 512, 2048);
    // rope + layout
    rope_kernel<<<dim3(4096), blk, 0, stream>>>(qb, kvb, kb, vTb);
    // attention
    attn_kernel<<<dim3(32, 8, 2), blk, 0, stream>>>(qb, kb, vTb, ob);
    // output projection
    gemm_bt<float><<<dim3(16, 32), blk, 0, stream>>>(ob, Wot, out, 4096, 2048, 2048);
}

// Round 4
// 387.675 us; speedup vs baseline: 2.2727x; 1.1332x over previous
//
#include <hip/hip_runtime.h>
#include <hip/hip_bf16.h>

typedef __bf16 bf16x8 __attribute__((ext_vector_type(8)));
typedef __bf16 bf16x4 __attribute__((ext_vector_type(4)));
typedef float  f32x4  __attribute__((ext_vector_type(4)));

#define MFMA16(a, b, c) __builtin_amdgcn_mfma_f32_16x16x32_bf16((a), (b), (c), 0, 0, 0)

#define GLOBAL_AS(p) ((const __attribute__((address_space(1))) void*)(p))
#define LDS_AS(p)    ((__attribute__((address_space(3))) void*)(p))

// ---------------------------------------------------------------------------
// fp32 -> bf16 elementwise convert.  Each thread converts 8 elements.
// ---------------------------------------------------------------------------
__global__ __launch_bounds__(256) void cvt_bf16_kernel(const float* __restrict__ in,
                                                       __bf16* __restrict__ out)
{
    const int idx = blockIdx.x * 256 + threadIdx.x;
    const float4* p = (const float4*)in + (size_t)idx * 2;
    float4 a = p[0], b = p[1];
    bf16x8 o;
    o[0] = (__bf16)a.x; o[1] = (__bf16)a.y; o[2] = (__bf16)a.z; o[3] = (__bf16)a.w;
    o[4] = (__bf16)b.x; o[5] = (__bf16)b.y; o[6] = (__bf16)b.z; o[7] = (__bf16)b.w;
    ((bf16x8*)out)[idx] = o;
}

// ---------------------------------------------------------------------------
// RoPE cos/sin table: cs[s][i] = {cos, sin}(s * 10000^(-i/128)).
// grid 2048, 128 threads.
// ---------------------------------------------------------------------------
__global__ __launch_bounds__(128) void trig_kernel(float2* __restrict__ cs)
{
    const int s = blockIdx.x, i = threadIdx.x;
    const float theta = (float)s * exp2f((float)i * (-13.287712379549449f / 128.f));
    float sn, c;
    sincosf(theta, &sn, &c);
    cs[s * 128 + i] = make_float2(c, sn);
}

// ---------------------------------------------------------------------------
// Transpose + convert: Bt[n][k] = (bf16)W[k][n].  W is K x N fp32.
// block (32,8), grid (N/32, K/32).
// ---------------------------------------------------------------------------
__global__ __launch_bounds__(256) void transpose_cvt_kernel(const float* __restrict__ W,
                                                            __bf16* __restrict__ Bt,
                                                            int K, int N)
{
    __shared__ float t[32][33];
    const int n0 = blockIdx.x * 32, k0 = blockIdx.y * 32;
    const int x = threadIdx.x, y = threadIdx.y;
#pragma unroll
    for (int r = 0; r < 4; ++r)
        t[y + r * 8][x] = W[(size_t)(k0 + y + r * 8) * N + n0 + x];
    __syncthreads();
#pragma unroll
    for (int r = 0; r < 4; ++r)
        Bt[(size_t)(n0 + y + r * 8) * K + k0 + x] = (__bf16)t[x][y + r * 8];
}

// ---------------------------------------------------------------------------
// bf16 transpose for V: vT[b][d][s] = qkv[b*2048+s][2304+d].
// block (32,8), grid (S/32, D/32, B).
// ---------------------------------------------------------------------------
__global__ __launch_bounds__(256) void vt_kernel(const __bf16* __restrict__ qkv,
                                                 __bf16* __restrict__ vT)
{
    __shared__ __bf16 t[32][33];
    const int s0 = blockIdx.x * 32, d0 = blockIdx.y * 32, b = blockIdx.z;
    const int x = threadIdx.x, y = threadIdx.y;
#pragma unroll
    for (int r = 0; r < 4; ++r)
        t[y + r * 8][x] = qkv[(size_t)(b * 2048 + s0 + y + r * 8) * 2560 + 2304 + d0 + x];
    __syncthreads();
#pragma unroll
    for (int r = 0; r < 4; ++r)
        vT[(size_t)(b * 256 + d0 + y + r * 8) * 2048 + s0 + x] = t[x][y + r * 8];
}

// ---------------------------------------------------------------------------
// GEMM (m97 structure): C[M][N] = A[M][K] * Bt[N][K]^T, bf16 inputs.
// Block 256 thr (4 waves 2x2), tile 128x128, BK=32.
// Staging via global_load_lds width=16 (contiguous LDS, no padding).
// ---------------------------------------------------------------------------
template <typename TC>
__global__ __launch_bounds__(256) void gemm_bt(const __bf16* __restrict__ A,
                                               const __bf16* __restrict__ Bt,
                                               TC* __restrict__ C,
                                               int M, int N, int K)
{
    __shared__ __bf16 As[128 * 32];
    __shared__ __bf16 Bs[128 * 32];

    const int tid  = threadIdx.x;
    const int wave = tid >> 6, lane = tid & 63;
    const int quad = lane >> 4, l16 = lane & 15;
    const int wm = (wave >> 1) * 64, wn = (wave & 1) * 64;
    const int bm = blockIdx.y * 128, bn = blockIdx.x * 128;

    f32x4 acc[4][4] = {};

    for (int k0 = 0; k0 < K; k0 += 32) {
        __syncthreads();
#pragma unroll
        for (int c = 0; c < 2; ++c) {
            const int off = tid * 16 + c * 4096;   // byte offset into 8 KB tile
            const int row = off >> 6;              // 64 B (32 bf16) per row
            const int kb  = (off & 63) >> 1;       // bf16 offset within row
            const __bf16* ga = A  + (size_t)(bm + row) * K + k0 + kb;
            const __bf16* gb = Bt + (size_t)(bn + row) * K + k0 + kb;
            __builtin_amdgcn_global_load_lds(GLOBAL_AS(ga), LDS_AS(As + (off >> 1)), 16, 0, 0);
            __builtin_amdgcn_global_load_lds(GLOBAL_AS(gb), LDS_AS(Bs + (off >> 1)), 16, 0, 0);
        }
        __syncthreads();   // vmcnt(0) drain -> tile visible

        bf16x8 af[4];
#pragma unroll
        for (int mi = 0; mi < 4; ++mi)
            af[mi] = *(const bf16x8*)&As[(wm + mi * 16 + l16) * 32 + quad * 8];
#pragma unroll
        for (int ni = 0; ni < 4; ++ni) {
            bf16x8 bfr = *(const bf16x8*)&Bs[(wn + ni * 16 + l16) * 32 + quad * 8];
#pragma unroll
            for (int mi = 0; mi < 4; ++mi)
                acc[mi][ni] = MFMA16(af[mi], bfr, acc[mi][ni]);
        }
    }
    // C/D layout: col = lane&15, row = quad*4 + reg
#pragma unroll
    for (int mi = 0; mi < 4; ++mi)
#pragma unroll
        for (int ni = 0; ni < 4; ++ni)
#pragma unroll
            for (int r = 0; r < 4; ++r) {
                int row = bm + wm + mi * 16 + quad * 4 + r;
                int col = bn + wn + ni * 16 + l16;
                C[(size_t)row * N + col] = (TC)acc[mi][ni][r];
            }
}

// ---------------------------------------------------------------------------
// RoPE in place on fused qkv[4096][2560] (q cols 0..2047, k cols 2048..2303).
// q pre-scaled by log2(e)/16.  Vectorized bf16x4, table-driven cos/sin.
// grid = B*S blocks, 256 threads.
// ---------------------------------------------------------------------------
__global__ __launch_bounds__(256) void rope_kernel(__bf16* __restrict__ qkv,
                                                   const float2* __restrict__ cs)
{
    const int bs = blockIdx.x;              // b*2048 + s
    const int s = bs & 2047;
    const int t = threadIdx.x;
    const float QS = 0.09016843787599907f;  // log2(e) / sqrt(D)

    // q: 8 heads x 128 pairs; thread handles 4 consecutive pairs of head t>>5
    const int hh = t >> 5, i0 = (t & 31) * 4;
    float2 c0 = cs[s * 128 + i0 + 0], c1 = cs[s * 128 + i0 + 1];
    float2 c2 = cs[s * 128 + i0 + 2], c3 = cs[s * 128 + i0 + 3];

    {
        __bf16* p = qkv + (size_t)bs * 2560 + hh * 256 + i0;
        bf16x4 x1 = *(const bf16x4*)p;
        bf16x4 x2 = *(const bf16x4*)(p + 128);
        bf16x4 o1, o2;
        o1[0] = (__bf16)(((float)x1[0] * c0.x - (float)x2[0] * c0.y) * QS);
        o2[0] = (__bf16)(((float)x2[0] * c0.x + (float)x1[0] * c0.y) * QS);
        o1[1] = (__bf16)(((float)x1[1] * c1.x - (float)x2[1] * c1.y) * QS);
        o2[1] = (__bf16)(((float)x2[1] * c1.x + (float)x1[1] * c1.y) * QS);
        o1[2] = (__bf16)(((float)x1[2] * c2.x - (float)x2[2] * c2.y) * QS);
        o2[2] = (__bf16)(((float)x2[2] * c2.x + (float)x1[2] * c2.y) * QS);
        o1[3] = (__bf16)(((float)x1[3] * c3.x - (float)x2[3] * c3.y) * QS);
        o2[3] = (__bf16)(((float)x2[3] * c3.x + (float)x1[3] * c3.y) * QS);
        *(bf16x4*)p = o1;
        *(bf16x4*)(p + 128) = o2;
    }
    if (t < 32) {   // k: 128 pairs, 4 per thread (no QS scale)
        const int j0 = t * 4;
        float2 d0 = cs[s * 128 + j0 + 0], d1 = cs[s * 128 + j0 + 1];
        float2 d2 = cs[s * 128 + j0 + 2], d3 = cs[s * 128 + j0 + 3];
        __bf16* p = qkv + (size_t)bs * 2560 + 2048 + j0;
        bf16x4 x1 = *(const bf16x4*)p;
        bf16x4 x2 = *(const bf16x4*)(p + 128);
        bf16x4 o1, o2;
        o1[0] = (__bf16)((float)x1[0] * d0.x - (float)x2[0] * d0.y);
        o2[0] = (__bf16)((float)x2[0] * d0.x + (float)x1[0] * d0.y);
        o1[1] = (__bf16)((float)x1[1] * d1.x - (float)x2[1] * d1.y);
        o2[1] = (__bf16)((float)x2[1] * d1.x + (float)x1[1] * d1.y);
        o1[2] = (__bf16)((float)x1[2] * d2.x - (float)x2[2] * d2.y);
        o2[2] = (__bf16)((float)x2[2] * d2.x + (float)x1[2] * d2.y);
        o1[3] = (__bf16)((float)x1[3] * d3.x - (float)x2[3] * d3.y);
        o2[3] = (__bf16)((float)x2[3] * d3.x + (float)x1[3] * d3.y);
        *(bf16x4*)p = o1;
        *(bf16x4*)(p + 128) = o2;
    }
}

// ---------------------------------------------------------------------------
// Flash attention (causal), LDS-staged K/Vt, XOR-swizzled, async staging.
// grid = (32 qt, H, B), 256 thr (4 waves).  K-tile = 64 keys.
// Vs has 16 extra all-ones rows (d=256..271): the 17th PV d-tile computes
// the softmax denominator l via MFMA (alpha-rescale comes free with oacc),
// replacing the per-iter sum-shuffle reduction.
// P LDS pad = 68: quad row-offset = 8 banks -> conflict-free P writes.
// LDS: K 32 KB + Vs 34 KB + P 8.5 KB = 74.5 KB -> 2 blocks/CU.
// ---------------------------------------------------------------------------
__global__ __launch_bounds__(256) void attn_kernel(const __bf16* __restrict__ qkv,
                                                   const __bf16* __restrict__ vTg,
                                                   __bf16* __restrict__ og)
{
    __shared__ __bf16 Ks[64 * 256];    // 64 keys x 256 d (swizzled), 32 KB
    __shared__ __bf16 Vs[272 * 64];    // 256 d x 64 keys (swizzled) + 16 ones rows
    __shared__ __bf16 Ps[4][16][68];   // per-wave P [qrow][key], pad 64->68

    const int b = blockIdx.z, h = blockIdx.y;
    const int qt = (int)gridDim.x - 1 - (int)blockIdx.x;
    const int q0 = qt * 64;
    const int tid  = threadIdx.x;
    const int wave = tid >> 6, lane = tid & 63;
    const int quad = lane >> 4, l16 = lane & 15;
    const int xork = l16 & 7;          // swizzle key for fragment reads

    // ones rows for the l-tile (written once; visible after first tile barrier)
    if (tid < 128) {
        bf16x8 one;
#pragma unroll
        for (int e = 0; e < 8; ++e) one[e] = (__bf16)1.0f;
        *(bf16x8*)&Vs[256 * 64 + tid * 8] = one;
    }

    // Q fragments (A-layout: m = lane&15, k = quad*8 + j); q row stride 2560
    const int qrow = q0 + wave * 16 + l16;
    const __bf16* qptr = qkv + (size_t)(b * 2048 + qrow) * 2560 + h * 256;
    bf16x8 qf[8];
#pragma unroll
    for (int dc = 0; dc < 8; ++dc)
        qf[dc] = *(const bf16x8*)(qptr + dc * 32 + quad * 8);

    f32x4 oacc[17] = {};               // [16] = l-tile
    float m_r[4] = {-1e30f, -1e30f, -1e30f, -1e30f};

    // ---- staging address precompute (j0-independent) ----
    // K tile: 64 rows x 32 chunks; row stride in qkv = 2560.
    const int kKey0 = tid >> 5;                       // 0..7
    const int kC    = (tid & 31) ^ (kKey0 & 7);
    const __bf16* kstage0 = qkv + (size_t)b * 2048 * 2560 + 2048
                          + (size_t)kKey0 * 2560 + kC * 8;
    // V tile: 256 rows x 8 chunks; vT row stride 2048.
    const int vD0 = tid >> 3;                         // 0..31
    const int vC  = (tid & 7) ^ (vD0 & 7);
    const __bf16* vstage0 = vTg + (size_t)b * 256 * 2048 + (size_t)vD0 * 2048 + vC * 8;

    int ckK[8];
#pragma unroll
    for (int dc = 0; dc < 8; ++dc) ckK[dc] = (dc * 4 + quad) ^ xork;
    const int chV0 = quad ^ xork;          // V slot for keys 0..31
    const int chV1 = (4 + quad) ^ xork;    // V slot for keys 32..63

    for (int j0 = 0; j0 <= q0; j0 += 64) {
        __syncthreads();
        const __bf16* kst = kstage0 + (size_t)j0 * 2560;
        const __bf16* vst = vstage0 + j0;
#pragma unroll
        for (int p = 0; p < 8; ++p)
            __builtin_amdgcn_global_load_lds(GLOBAL_AS(kst + (size_t)p * 8 * 2560),
                                             LDS_AS(Ks + tid * 8 + p * 2048), 16, 0, 0);
#pragma unroll
        for (int p = 0; p < 8; ++p)
            __builtin_amdgcn_global_load_lds(GLOBAL_AS(vst + (size_t)p * 32 * 2048),
                                             LDS_AS(Vs + tid * 8 + p * 2048), 16, 0, 0);
        __syncthreads();   // vmcnt(0) drain -> tile visible

        // ---- S = Q K^T over 64 keys (4 n-tiles) ----
        f32x4 sc[4] = {};
#pragma unroll
        for (int nt = 0; nt < 4; ++nt) {
            const __bf16* krow = &Ks[(nt * 16 + l16) * 256];
#pragma unroll
            for (int dc = 0; dc < 8; ++dc) {
                bf16x8 kf = *(const bf16x8*)(krow + ckK[dc] * 8);
                sc[nt] = MFMA16(qf[dc], kf, sc[nt]);
            }
        }
        if (j0 == q0) {   // diagonal tile: causal mask
#pragma unroll
            for (int nt = 0; nt < 4; ++nt) {
                int key = j0 + nt * 16 + l16;
#pragma unroll
                for (int r = 0; r < 4; ++r) {
                    int row = q0 + wave * 16 + quad * 4 + r;
                    if (key > row) sc[nt][r] = -1e30f;
                }
            }
        }
        // ---- online softmax (exp2 domain; l comes from the MFMA ones-tile) --
#pragma unroll
        for (int r = 0; r < 4; ++r) {
            float mx = fmaxf(fmaxf(sc[0][r], sc[1][r]), fmaxf(sc[2][r], sc[3][r]));
#pragma unroll
            for (int off = 1; off < 16; off <<= 1)
                mx = fmaxf(mx, __shfl_xor(mx, off, 64));
            float mnew  = fmaxf(m_r[r], mx);
            float alpha = exp2f(m_r[r] - mnew);
            m_r[r] = mnew;
#pragma unroll
            for (int nt = 0; nt < 4; ++nt)
                sc[nt][r] = exp2f(sc[nt][r] - mnew);
#pragma unroll
            for (int t = 0; t < 17; ++t)
                oacc[t][r] *= alpha;
        }
        // ---- P: C-layout -> per-wave LDS -> A-layout (in-order, no barrier) --
#pragma unroll
        for (int nt = 0; nt < 4; ++nt)
#pragma unroll
            for (int r = 0; r < 4; ++r)
                Ps[wave][quad * 4 + r][nt * 16 + l16] = (__bf16)sc[nt][r];
        bf16x8 pf0 = *(const bf16x8*)&Ps[wave][l16][quad * 8];
        bf16x8 pf1 = *(const bf16x8*)&Ps[wave][l16][32 + quad * 8];
        // ---- O += P V (17 d-tiles x 2 key-halves; dt=16 accumulates l) ----
#pragma unroll
        for (int dt = 0; dt < 17; ++dt) {
            const __bf16* vrow = &Vs[(dt * 16 + l16) * 64];
            bf16x8 vf0 = *(const bf16x8*)(vrow + chV0 * 8);
            bf16x8 vf1 = *(const bf16x8*)(vrow + chV1 * 8);
            oacc[dt] = MFMA16(pf0, vf0, oacc[dt]);
            oacc[dt] = MFMA16(pf1, vf1, oacc[dt]);
        }
    }
    // ---- normalize + store ----
    float invl[4];
#pragma unroll
    for (int r = 0; r < 4; ++r) invl[r] = 1.f / oacc[16][r];
#pragma unroll
    for (int dt = 0; dt < 16; ++dt)
#pragma unroll
        for (int r = 0; r < 4; ++r) {
            int row = q0 + wave * 16 + quad * 4 + r;
            int col = h * 256 + dt * 16 + l16;
            og[(size_t)(b * 2048 + row) * 2048 + col] = (__bf16)(oacc[dt][r] * invl[r]);
        }
}

// ---------------------------------------------------------------------------
// Workspace layout (byte offsets, MiB):
//   hb    [4096][2048] bf16 @  0   (16)  hidden in bf16
//   qkv   [4096][2560] bf16 @ 16   (20)  fused Q|K|V projection
//   vT    [2][256][2048]    @ 36   ( 2)
//   ob    [4096][2048] bf16 @ 38   (16)  attention output
//   Wqkvt [2560][2048] bf16 @ 54   (10)
//   Wot   [2048][2048] bf16 @ 64   ( 8)
//   cs    [2048][128] float2 @ 72  ( 2)  total 74 MiB
// ---------------------------------------------------------------------------
extern "C" void kernel_launch(void* const* d_in, const int* in_sizes, int n_in,
                              void* d_out, int out_size, void* d_ws, size_t ws_size,
                              hipStream_t stream)
{
    (void)in_sizes; (void)n_in; (void)out_size; (void)ws_size;
    const float* hidden = (const float*)d_in[0];
    const float* Wq = (const float*)d_in[3];
    const float* Wk = (const float*)d_in[4];
    const float* Wv = (const float*)d_in[5];
    const float* Wo = (const float*)d_in[6];

    char* ws = (char*)d_ws;
    __bf16* hb    = (__bf16*)(ws);
    __bf16* qkv   = (__bf16*)(ws + (16u << 20));
    __bf16* vTb   = (__bf16*)(ws + (36u << 20));
    __bf16* ob    = (__bf16*)(ws + (38u << 20));
    __bf16* Wqkvt = (__bf16*)(ws + (54u << 20));
    __bf16* Wot   = (__bf16*)(ws + (64u << 20));
    float2* csb   = (float2*)(ws + (72u << 20));
    float* out = (float*)d_out;

    dim3 blk(256);
    dim3 tblk(32, 8);
    // prep: convert + trig table + transposed weights
    cvt_bf16_kernel<<<dim3(4096), blk, 0, stream>>>(hidden, hb);
    trig_kernel<<<dim3(2048), dim3(128), 0, stream>>>(csb);
    transpose_cvt_kernel<<<dim3(64, 64), tblk, 0, stream>>>(Wq, Wqkvt, 2048, 2048);
    transpose_cvt_kernel<<<dim3(8, 64), tblk, 0, stream>>>(Wk, Wqkvt + (size_t)2048 * 2048, 2048, 256);
    transpose_cvt_kernel<<<dim3(8, 64), tblk, 0, stream>>>(Wv, Wqkvt + (size_t)2304 * 2048, 2048, 256);
    transpose_cvt_kernel<<<dim3(64, 64), tblk, 0, stream>>>(Wo, Wot, 2048, 2048);
    // fused QKV projection
    gemm_bt<__bf16><<<dim3(20, 32), blk, 0, stream>>>(hb, Wqkvt, qkv, 4096, 2560, 2048);
    // rope (q,k in place) + v transpose
    rope_kernel<<<dim3(4096), blk, 0, stream>>>(qkv, csb);
    vt_kernel<<<dim3(64, 8, 2), tblk, 0, stream>>>(qkv, vTb);
    // attention
    attn_kernel<<<dim3(32, 8, 2), blk, 0, stream>>>(qkv, vTb, ob);
    // output projection
    gemm_bt<float><<<dim3(16, 32), blk, 0, stream>>>(ob, Wot, out, 4096, 2048, 2048);
}